// Round 3
// baseline (1611.856 us; speedup 1.0000x reference)
//
#include <hip/hip_runtime.h>
#include <cstdint>

typedef __bf16 bf16;
typedef __attribute__((ext_vector_type(8))) __bf16 bf16x8;
typedef __attribute__((ext_vector_type(4))) float f32x4;

#define MTOT (8*128*128)   // 131072 tokens total
#define MCH  16384         // tokens per chunk (one batch image: 128*128)

// ---------------------------------------------------------------------------
// Weight transpose + cast: in fp32 (R x C) -> out bf16 (C x R), dims % 32 == 0
// ---------------------------------------------------------------------------
__global__ __launch_bounds__(256)
void transpose_cast_kernel(const float* __restrict__ in, bf16* __restrict__ out,
                           int R, int C) {
    __shared__ float tile[32][33];
    const int tx = threadIdx.x & 31, ty = threadIdx.x >> 5;
    const int c0 = blockIdx.x * 32, r0 = blockIdx.y * 32;
#pragma unroll
    for (int r = ty; r < 32; r += 8) tile[r][tx] = in[(size_t)(r0 + r) * C + c0 + tx];
    __syncthreads();
#pragma unroll
    for (int r = ty; r < 32; r += 8) out[(size_t)(c0 + r) * R + r0 + tx] = (bf16)tile[tx][r];
}

// ---------------------------------------------------------------------------
// Row l2-normalize: fp32 in (320/token) -> bf16 out. 1 wave/token, 4/block.
// 320 = 5 * 64, so each lane handles exactly 5 elements — no predicates.
// ---------------------------------------------------------------------------
__global__ __launch_bounds__(256)
void l2norm_kernel(const float* __restrict__ X, bf16* __restrict__ O) {
    const int tid = threadIdx.x, wv = tid >> 6, lane = tid & 63;
    const size_t row = (size_t)blockIdx.x * 4 + wv;
    const float* xr = X + row * 320;
    bf16* orow = O + row * 320;
    float v[5];
    float ss = 0.f;
#pragma unroll
    for (int r = 0; r < 5; ++r) {
        v[r] = xr[r * 64 + lane];
        ss += v[r] * v[r];
    }
#pragma unroll
    for (int off = 32; off; off >>= 1) ss += __shfl_xor(ss, off);
    const float sc = 1.f / fmaxf(sqrtf(ss), 1e-12f);
#pragma unroll
    for (int r = 0; r < 5; ++r) orow[r * 64 + lane] = (bf16)(v[r] * sc);
}

// ---------------------------------------------------------------------------
// GEMM: out(MxN) = A(MxK) @ WT(NxK)^T [+ epilogue]. BM=128, BN=64, BK=32.
// A, WT bf16; accumulate fp32; OutT = bf16 or float.
// EPI: 0 = +bias   1 = relu(acc)   2 = res + relu(acc+bias)*gamma
// ---------------------------------------------------------------------------
template <int EPI, typename OutT>
__global__ __launch_bounds__(256)
void gemm_kernel(const bf16* __restrict__ A, const bf16* __restrict__ WT,
                 const float* __restrict__ bias, const bf16* res,
                 const float* __restrict__ gamma, OutT* __restrict__ out,
                 int K, int N) {
    __shared__ bf16 As[128 * 32];   // 8 KB
    __shared__ bf16 Bs[64 * 32];    // 4 KB
    const int tid = threadIdx.x;
    const int wv = tid >> 6, lane = tid & 63;
    const int n0 = blockIdx.x * 64;
    const int m0 = blockIdx.y * 128;
    const int r0 = lane & 15, qd = lane >> 4;

    f32x4 acc[2][4];
#pragma unroll
    for (int i = 0; i < 2; ++i)
#pragma unroll
        for (int j = 0; j < 4; ++j)
#pragma unroll
            for (int r = 0; r < 4; ++r) acc[i][j][r] = 0.f;

    // staging map: thread t handles row t/4, k-chunk (t%4)*8 (16B per thread)
    const int sr = tid >> 2, sc = (tid & 3) << 3;
    const bf16* Ag0 = A + (size_t)(m0 + sr) * K + sc;
    const bf16* Ag1 = Ag0 + (size_t)64 * K;
    const bf16* Bg  = WT + (size_t)(n0 + sr) * K + sc;

    const bf16* a0p = As + (32 * wv + r0) * 32 + qd * 8;
    const bf16* a1p = a0p + 16 * 32;

    for (int kk = 0; kk < K; kk += 32) {
        bf16x8 ra0 = *(const bf16x8*)(Ag0 + kk);
        bf16x8 ra1 = *(const bf16x8*)(Ag1 + kk);
        bf16x8 rb  = *(const bf16x8*)(Bg + kk);
        __syncthreads();                       // prior iter's LDS reads done
        *(bf16x8*)(As + tid * 8)        = ra0;
        *(bf16x8*)(As + 2048 + tid * 8) = ra1;
        *(bf16x8*)(Bs + tid * 8)        = rb;
        __syncthreads();                       // LDS visible to all waves
        bf16x8 a0 = *(const bf16x8*)a0p;
        bf16x8 a1 = *(const bf16x8*)a1p;
#pragma unroll
        for (int j = 0; j < 4; ++j) {
            bf16x8 b = *(const bf16x8*)(Bs + (16 * j + r0) * 32 + qd * 8);
            acc[0][j] = __builtin_amdgcn_mfma_f32_16x16x32_bf16(a0, b, acc[0][j], 0, 0, 0);
            acc[1][j] = __builtin_amdgcn_mfma_f32_16x16x32_bf16(a1, b, acc[1][j], 0, 0, 0);
        }
    }

    // D layout: lane holds col = lane&15, rows quad*4 + r  [m89/m91-verified]
#pragma unroll
    for (int i = 0; i < 2; ++i) {
        const int rb2 = m0 + 32 * wv + 16 * i + qd * 4;
#pragma unroll
        for (int j = 0; j < 4; ++j) {
            const int col = n0 + 16 * j + r0;
            float bv = (EPI != 1) ? bias[col] : 0.f;
            float gv = (EPI == 2) ? gamma[col] : 0.f;
#pragma unroll
            for (int r = 0; r < 4; ++r) {
                const size_t row = (size_t)(rb2 + r);
                float v = acc[i][j][r];
                if (EPI == 0)      v += bv;
                else if (EPI == 1) v = fmaxf(v, 0.f);
                else               v = (float)res[row * (size_t)N + col] + fmaxf(v + bv, 0.f) * gv;
                out[row * (size_t)N + col] = (OutT)v;
            }
        }
    }
}

// ---------------------------------------------------------------------------
// Attention on one 16384-token chunk (one batch image, 128x128 grid).
// One wave per (window, head); lane = token in 8x8 window.
// QKV row layout per token: head h -> [h*30 .. h*30+10) q, +10 k, +20 v.
// ---------------------------------------------------------------------------
__global__ __launch_bounds__(256)
void attn_kernel(const bf16* __restrict__ QKV, bf16* __restrict__ AO) {
    __shared__ float kvs[4][64][20];   // per wave: k[64][10], v[64][10]
    const int tid = threadIdx.x, wv = tid >> 6, lane = tid & 63;
    const int p = blockIdx.x * 4 + wv;       // pair id, 0..8191
    const int w = p >> 5, h = p & 31;        // window 0..255, head 0..31
    const int wh = w >> 4, ww = w & 15;
    const size_t tok = (size_t)(wh * 8 + (lane >> 3)) * 128 + (size_t)(ww * 8 + (lane & 7));
    const bf16* qb = QKV + tok * 960 + h * 30;
    float q[10];
#pragma unroll
    for (int d = 0; d < 10; ++d) q[d] = (float)qb[d];
#pragma unroll
    for (int d = 0; d < 10; ++d) kvs[wv][lane][d] = (float)qb[10 + d];
#pragma unroll
    for (int d = 0; d < 10; ++d) kvs[wv][lane][10 + d] = (float)qb[20 + d];
    __syncthreads();

    float s[64];
    float mx = -1e30f;
#pragma unroll
    for (int t = 0; t < 64; ++t) {
        float d = 0.f;
#pragma unroll
        for (int e = 0; e < 10; ++e) d += q[e] * kvs[wv][t][e];
        d *= 0.31622776601683794f;   // 10^-0.5
        s[t] = d; mx = fmaxf(mx, d);
    }
    float sum = 0.f;
#pragma unroll
    for (int t = 0; t < 64; ++t) { s[t] = __expf(s[t] - mx); sum += s[t]; }
    const float inv = 1.f / sum;
    float o[10];
#pragma unroll
    for (int e = 0; e < 10; ++e) o[e] = 0.f;
#pragma unroll
    for (int t = 0; t < 64; ++t) {
        const float pw = s[t];
#pragma unroll
        for (int e = 0; e < 10; ++e) o[e] += pw * kvs[wv][t][10 + e];
    }
    bf16* ob = AO + tok * 320 + h * 10;
#pragma unroll
    for (int e = 0; e < 10; ++e) ob[e] = (bf16)(o[e] * inv);
}

// ---------------------------------------------------------------------------
// Fused proj (+bias) + residual + l2norm. BM=64, BN=320 (full width) so the
// per-token norm reduces inside the quad. Z aliases XN (in-place safe: each
// (row,col) is read then written by exactly one lane of one wave).
// ---------------------------------------------------------------------------
__global__ __launch_bounds__(256)
void proj_norm_kernel(const bf16* __restrict__ AO, const bf16* __restrict__ PT,
                      const float* __restrict__ pb, const bf16* XN, bf16* Z) {
    __shared__ bf16 As[64 * 32];     // 4 KB
    __shared__ bf16 Bs[320 * 32];    // 20 KB
    const int tid = threadIdx.x, wv = tid >> 6, lane = tid & 63;
    const int m0 = blockIdx.x * 64;
    const int r0 = lane & 15, qd = lane >> 4;

    f32x4 acc[20];
#pragma unroll
    for (int j = 0; j < 20; ++j)
#pragma unroll
        for (int r = 0; r < 4; ++r) acc[j][r] = 0.f;

    const int sr = tid >> 2, sc = (tid & 3) << 3;
    const bf16* Ag = AO + (size_t)(m0 + sr) * 320 + sc;
    const bf16* Bg = PT + (size_t)sr * 320 + sc;

    for (int kk = 0; kk < 320; kk += 32) {
        bf16x8 ra = *(const bf16x8*)(Ag + kk);
        bf16x8 rb[5];
#pragma unroll
        for (int p = 0; p < 5; ++p) rb[p] = *(const bf16x8*)(Bg + (size_t)(p * 64) * 320 + kk);
        __syncthreads();
        *(bf16x8*)(As + tid * 8) = ra;
#pragma unroll
        for (int p = 0; p < 5; ++p) *(bf16x8*)(Bs + p * 2048 + tid * 8) = rb[p];
        __syncthreads();
        bf16x8 a = *(const bf16x8*)(As + (16 * wv + r0) * 32 + qd * 8);
#pragma unroll
        for (int j = 0; j < 20; ++j) {
            bf16x8 b = *(const bf16x8*)(Bs + (16 * j + r0) * 32 + qd * 8);
            acc[j] = __builtin_amdgcn_mfma_f32_16x16x32_bf16(a, b, acc[j], 0, 0, 0);
        }
    }

#pragma unroll
    for (int r = 0; r < 4; ++r) {
        const size_t row = (size_t)(m0 + 16 * wv + qd * 4 + r);
        float y[20];
        float ss = 0.f;
#pragma unroll
        for (int j = 0; j < 20; ++j) {
            const int col = 16 * j + r0;
            float v = acc[j][r] + pb[col] + (float)XN[row * 320 + col];
            y[j] = v; ss += v * v;
        }
        // reduce across the 16 lanes of this quad (they share the token)
        ss += __shfl_xor(ss, 1);
        ss += __shfl_xor(ss, 2);
        ss += __shfl_xor(ss, 4);
        ss += __shfl_xor(ss, 8);
        const float sc2 = 1.f / fmaxf(sqrtf(ss), 1e-12f);
#pragma unroll
        for (int j = 0; j < 20; ++j) Z[row * 320 + 16 * j + r0] = (bf16)(y[j] * sc2);
    }
}

// ---------------------------------------------------------------------------
extern "C" void kernel_launch(void* const* d_in, const int* in_sizes, int n_in,
                              void* d_out, int out_size, void* d_ws, size_t ws_size,
                              hipStream_t stream) {
    (void)in_sizes; (void)n_in; (void)out_size; (void)ws_size;
    const float* x      = (const float*)d_in[0];
    const float* qkv_w  = (const float*)d_in[1];
    const float* qkv_b  = (const float*)d_in[2];
    const float* proj_w = (const float*)d_in[3];
    const float* proj_b = (const float*)d_in[4];
    const float* gamma  = (const float*)d_in[5];
    const float* w1     = (const float*)d_in[6];
    const float* w2     = (const float*)d_in[7];
    const float* b2     = (const float*)d_in[8];
    float* out = (float*)d_out;

    char* ws = (char*)d_ws;
    // workspace layout (total ~62.3 MB):
    //   XNb @ 0          : MCH*320*2  = 10,485,760  (l2norm chunk; holds Z in-place)
    //   CH  @ 10,485,760 : 41,943,040 chunk region
    //        QKV_c = CH[0 .. 31,457,280)  (MCH x 960 bf16)
    //        H1_c  = CH[0 .. end)         (MCH x 1280 bf16, after attn phase)
    //   AO  @ 52,428,800 : 10,485,760     (MCH x 320 bf16)
    //   WT  @ 62,914,560 : 2,457,600 transposed bf16 weights
    bf16* XNb   = (bf16*)(ws);
    bf16* QKV_c = (bf16*)(ws + 10485760ull);
    bf16* H1_c  = QKV_c;
    bf16* AO_c  = (bf16*)(ws + 52428800ull);
    bf16* QT    = (bf16*)(ws + 62914560ull);
    bf16* PT    = QT + 960 * 320;
    bf16* W1T   = PT + 320 * 320;
    bf16* W2T   = W1T + 1280 * 320;

    transpose_cast_kernel<<<dim3(30, 10), 256, 0, stream>>>(qkv_w, QT, 320, 960);
    transpose_cast_kernel<<<dim3(10, 10), 256, 0, stream>>>(proj_w, PT, 320, 320);
    transpose_cast_kernel<<<dim3(40, 10), 256, 0, stream>>>(w1, W1T, 320, 1280);
    transpose_cast_kernel<<<dim3(10, 40), 256, 0, stream>>>(w2, W2T, 1280, 320);

    for (int c = 0; c < 8; ++c) {
        const float* x_c = x + (size_t)c * MCH * 320;
        float* out_c = out + (size_t)c * MCH * 320;

        l2norm_kernel<<<MCH / 4, 256, 0, stream>>>(x_c, XNb);

        // QKV projection: (MCH x 320) @ (320 x 960) + b
        gemm_kernel<0, bf16><<<dim3(15, MCH / 128), 256, 0, stream>>>(
            XNb, QT, qkv_b, nullptr, nullptr, QKV_c, 320, 960);

        attn_kernel<<<(256 * 32) / 4, 256, 0, stream>>>(QKV_c, AO_c);

        // proj + bias + residual + l2norm  (Z in-place over XNb)
        proj_norm_kernel<<<MCH / 64, 256, 0, stream>>>(AO_c, PT, proj_b, XNb, XNb);

        // MLP1: relu(Z @ w1)
        gemm_kernel<1, bf16><<<dim3(20, MCH / 128), 256, 0, stream>>>(
            XNb, W1T, nullptr, nullptr, nullptr, H1_c, 320, 1280);

        // MLP2: out = Z + relu(H1 @ w2 + b2) * gamma   (fp32 output)
        gemm_kernel<2, float><<<dim3(5, MCH / 128), 256, 0, stream>>>(
            H1_c, W2T, b2, XNb, gamma, out_c, 1280, 320);
    }
}